// Round 3
// baseline (265.407 us; speedup 1.0000x reference)
//
#include <hip/hip_runtime.h>

typedef unsigned short bf16_t;
typedef __attribute__((ext_vector_type(8))) short short8;
typedef __attribute__((ext_vector_type(4))) float f32x4;
typedef __attribute__((ext_vector_type(16))) float f32x16;
typedef __attribute__((ext_vector_type(4))) unsigned short usx4;

#define T_SEQ 2048
#define NHEAD 16

__device__ __forceinline__ unsigned short f2bf(float x) {
  union { float f; unsigned u; } v; v.f = x;
  unsigned r = v.u + 0x7fffu + ((v.u >> 16) & 1u);
  return (unsigned short)(r >> 16);
}

__device__ __forceinline__ void gld_lds16(const void* g, void* l) {
  __builtin_amdgcn_global_load_lds((const __attribute__((address_space(1))) void*)g,
                                   (__attribute__((address_space(3))) void*)l, 16, 0, 0);
}

__device__ __forceinline__ unsigned cvtpk(float lo, float hi) {
  unsigned r;
  asm("v_cvt_pk_bf16_f32 %0, %1, %2" : "=v"(r) : "v"(lo), "v"(hi));
  return r;
}

// ---------------- weight transpose + convert: W[K][N] f32 -> Wt[N][K] bf16 ----------------
__global__ __launch_bounds__(256) void wtrans(const float* __restrict__ w0, const float* __restrict__ w1,
                                              const float* __restrict__ w2, const float* __restrict__ w3,
                                              bf16_t* __restrict__ wt) {
  __shared__ float tile[32][33];
  const float* w = (blockIdx.z == 0) ? w0 : (blockIdx.z == 1) ? w1 : (blockIdx.z == 2) ? w2 : w3;
  bf16_t* o = wt + (size_t)blockIdx.z * 1024 * 1024;
  const int c = threadIdx.x & 31;
  const int r = threadIdx.x >> 5;  // 0..7
  const int k0 = blockIdx.y * 32, n0 = blockIdx.x * 32;
#pragma unroll
  for (int rr = 0; rr < 32; rr += 8)
    tile[r + rr][c] = w[(size_t)(k0 + r + rr) * 1024 + n0 + c];
  __syncthreads();
#pragma unroll
  for (int rr = 0; rr < 32; rr += 8)
    o[(size_t)(n0 + r + rr) * 1024 + k0 + c] = f2bf(tile[c][r + rr]);
}

// ---------------- 128x128 bf16 MFMA GEMM, N fixed = 1024, B pre-transposed ----------------
// AFP32: A is fp32, converted to bf16 during reg-staged LDS write (fused cvt).
// MODE 0: bf16 row-major out   MODE 1: bf16 row-major out * (0.125*log2e) (Q)
// MODE 2: bf16 V^T out  [(b*16+h)*64+d][t]   MODE 3: f32 row-major out
template<int MODE, bool AFP32>
__global__ __launch_bounds__(256) void gemm128(const void* __restrict__ A,
                                               const bf16_t* __restrict__ Bt,
                                               void* __restrict__ Cout, int K) {
  __shared__ bf16_t As[128 * 64];
  __shared__ bf16_t Bs[128 * 64];
  const int tid = threadIdx.x;
  const int lane = tid & 63;
  const int l15 = lane & 15;
  const int g = lane >> 4;
  const int wave = tid >> 6;
  const int wr = wave >> 1, wc = wave & 1;
  const int row0 = blockIdx.y * 128, col0 = blockIdx.x * 128;

  f32x4 acc[4][4];
#pragma unroll
  for (int m = 0; m < 4; ++m)
#pragma unroll
    for (int n = 0; n < 4; ++n) acc[m][n] = (f32x4){0.f, 0.f, 0.f, 0.f};

  const int r_st = tid >> 3;  // 0..31
  const int c_st = tid & 7;   // 16B bf16 chunk (8 elems) within a 64-elem row

  for (int kt = 0; kt < K; kt += 64) {
#pragma unroll
    for (int i = 0; i < 4; ++i) {
      const int r = r_st + i * 32;
      if constexpr (AFP32) {
        const float* Af = (const float*)A;
        const float4 f0 = *(const float4*)(Af + (size_t)(row0 + r) * K + kt + c_st * 8);
        const float4 f1 = *(const float4*)(Af + (size_t)(row0 + r) * K + kt + c_st * 8 + 4);
        union { short8 v; unsigned u[4]; } pk;
        pk.u[0] = cvtpk(f0.x, f0.y);
        pk.u[1] = cvtpk(f0.z, f0.w);
        pk.u[2] = cvtpk(f1.x, f1.y);
        pk.u[3] = cvtpk(f1.z, f1.w);
        *(short8*)(As + (size_t)(tid + i * 256) * 8) = pk.v;
      } else {
        const bf16_t* Ab = (const bf16_t*)A;
        gld_lds16(Ab + (size_t)(row0 + r) * K + kt + c_st * 8, As + (size_t)(tid + i * 256) * 8);
      }
      gld_lds16(Bt + (size_t)(col0 + r) * K + kt + c_st * 8, Bs + (size_t)(tid + i * 256) * 8);
    }
    __syncthreads();
#pragma unroll
    for (int ks = 0; ks < 2; ++ks) {
      short8 a[4], b[4];
#pragma unroll
      for (int m = 0; m < 4; ++m)
        a[m] = *(const short8*)(As + (wr * 64 + m * 16 + l15) * 64 + ks * 32 + g * 8);
#pragma unroll
      for (int n = 0; n < 4; ++n)
        b[n] = *(const short8*)(Bs + (wc * 64 + n * 16 + l15) * 64 + ks * 32 + g * 8);
      __builtin_amdgcn_s_setprio(1);
#pragma unroll
      for (int m = 0; m < 4; ++m)
#pragma unroll
        for (int n = 0; n < 4; ++n)
          acc[m][n] = __builtin_amdgcn_mfma_f32_16x16x32_bf16(a[m], b[n], acc[m][n], 0, 0, 0);
      __builtin_amdgcn_s_setprio(0);
    }
    __syncthreads();
  }

  if constexpr (MODE == 0 || MODE == 1) {
    const float sc = (MODE == 1) ? 0.18033688011112042f : 1.0f;  // 0.125 * log2(e)
    bf16_t* C = (bf16_t*)Cout;
#pragma unroll
    for (int m = 0; m < 4; ++m) {
      const int row = row0 + wr * 64 + m * 16 + g * 4;
#pragma unroll
      for (int n = 0; n < 4; ++n) {
        const int col = col0 + wc * 64 + n * 16 + l15;
#pragma unroll
        for (int i = 0; i < 4; ++i)
          C[(size_t)(row + i) * 1024 + col] = f2bf(acc[m][n][i] * sc);
      }
    }
  } else if constexpr (MODE == 2) {
    bf16_t* C = (bf16_t*)Cout;
#pragma unroll
    for (int m = 0; m < 4; ++m) {
      const int row = row0 + wr * 64 + m * 16 + g * 4;  // global m = b*2048 + t
      const int bb = row >> 11;
      const int t = row & 2047;
#pragma unroll
      for (int n = 0; n < 4; ++n) {
        const int col = col0 + wc * 64 + n * 16 + l15;  // h*64 + d
        const int hh = col >> 6, dd = col & 63;
        usx4 w = { f2bf(acc[m][n][0]), f2bf(acc[m][n][1]), f2bf(acc[m][n][2]), f2bf(acc[m][n][3]) };
        *(usx4*)(C + (((size_t)(bb * 16 + hh) * 64 + dd) * 2048 + t)) = w;
      }
    }
  } else {
    float* C = (float*)Cout;
#pragma unroll
    for (int m = 0; m < 4; ++m) {
      const int row = row0 + wr * 64 + m * 16 + g * 4;
#pragma unroll
      for (int n = 0; n < 4; ++n) {
        const int col = col0 + wc * 64 + n * 16 + l15;
#pragma unroll
        for (int i = 0; i < 4; ++i)
          C[(size_t)(row + i) * 1024 + col] = acc[m][n][i];
      }
    }
  }
}

// ---------------- flash attention, 32x32 MFMA, exp2 softmax, double-buffered ----------------
// Qh: [B*T][1024] bf16, pre-scaled by 0.125*log2e. Kh: [B*T][1024] bf16.
// Vt: [(b*16+h)*64+d][2048] bf16.  ao out: [B*T][1024] bf16.
// Block: 4 waves; each wave owns 32 q-rows (block 128) of one (b,h); KV tiles of 64.
// Double-buffered: STAGE(next) issued before compute(cur); one barrier per iter
// (syncthreads' vmcnt drain lands AFTER the compute phase hid the latency).
// QK acc initialized to -mrun so exp2 applies directly (no per-elem sub).
__global__ __launch_bounds__(256) void attn_fwd(const bf16_t* __restrict__ qh,
                                                const bf16_t* __restrict__ kh,
                                                const bf16_t* __restrict__ vt,
                                                bf16_t* __restrict__ ao) {
  __shared__ bf16_t smem[16384];  // 2 x (Ks 64*64 | Vs 64*64); buf0 reused as out-bounce
  const int tid = threadIdx.x;
  const int lane = tid & 63;
  const int l31 = lane & 31;
  const int half = lane >> 5;
  const int wave = tid >> 6;
  const int qblk = blockIdx.x;  // 0..15
  const int bh = blockIdx.y;    // 0..63
  const int b = bh >> 4, h = bh & 15;

  const int tq = qblk * 128 + wave * 32 + l31;
  const size_t qoff = (size_t)(b * T_SEQ + tq) * 1024 + h * 64;
  short8 qf[4];
#pragma unroll
  for (int ks = 0; ks < 4; ++ks)
    qf[ks] = *(const short8*)(qh + qoff + ks * 16 + half * 8);

  f32x16 ov0, ov1;
#pragma unroll
  for (int i = 0; i < 16; ++i) { ov0[i] = 0.f; ov1[i] = 0.f; }
  float mrun = 0.f, lrun = 0.f;

  const size_t kbase = (size_t)b * T_SEQ * 1024 + h * 64;
  const size_t vbase = (size_t)bh * 64 * T_SEQ;
  const int r_st = tid >> 3;  // 0..31
  const int cd = tid & 7;

  // stage K tile [64 tk][64 d] and V^T tile [64 d][64 tk], source-XOR-swizzled
  auto stage = [&](int kvt, int bufi) {
    bf16_t* Ks = smem + bufi * 8192;
    bf16_t* Vs = Ks + 4096;
    const int t0 = kvt * 64;
#pragma unroll
    for (int i = 0; i < 2; ++i) {
      const int r = r_st + i * 32;
      const int cs = cd ^ (r & 7);
      gld_lds16(kh + kbase + (size_t)(t0 + r) * 1024 + cs * 8, Ks + (size_t)(tid + i * 256) * 8);
      gld_lds16(vt + vbase + (size_t)r * T_SEQ + t0 + cs * 8,  Vs + (size_t)(tid + i * 256) * 8);
    }
  };

  stage(0, 0);
  __syncthreads();

  for (int kv = 0; kv < T_SEQ / 64; ++kv) {
    const int cur = kv & 1;
    if (kv + 1 < T_SEQ / 64) stage(kv + 1, cur ^ 1);
    const bf16_t* Ks = smem + cur * 8192;
    const bf16_t* Vs = Ks + 4096;

    // S^T: 2 tiles of 32 tk x 32 tq; acc pre-biased with -mrun
    f32x16 st[2];
    const float negm = -mrun;
#pragma unroll
    for (int t = 0; t < 2; ++t)
#pragma unroll
      for (int i = 0; i < 16; ++i) st[t][i] = negm;
    __builtin_amdgcn_s_setprio(1);
#pragma unroll
    for (int t = 0; t < 2; ++t) {
      const int row = t * 32 + l31;
#pragma unroll
      for (int ks = 0; ks < 4; ++ks) {
        const short8 af = *(const short8*)(Ks + row * 64 + (((ks * 2 + half) ^ (l31 & 7)) * 8));
        st[t] = __builtin_amdgcn_mfma_f32_32x32x16_bf16(af, qf[ks], st[t], 0, 0, 0);
      }
    }
    __builtin_amdgcn_s_setprio(0);

    // column max via two v_max3 chains; st already holds S - mrun
    float pa = fmaxf(st[0][0], st[0][1]);
    float pb = fmaxf(st[0][2], st[0][3]);
#pragma unroll
    for (int i = 4; i < 16; i += 4) {
      pa = fmaxf(fmaxf(pa, st[0][i]), st[0][i + 1]);
      pb = fmaxf(fmaxf(pb, st[0][i + 2]), st[0][i + 3]);
    }
#pragma unroll
    for (int i = 0; i < 16; i += 4) {
      pa = fmaxf(fmaxf(pa, st[1][i]), st[1][i + 1]);
      pb = fmaxf(fmaxf(pb, st[1][i + 2]), st[1][i + 3]);
    }
    float pm = fmaxf(pa, pb);
    pm = fmaxf(pm, __shfl_xor(pm, 32));

    if (__any(pm > 8.f)) {  // defer-max: P bounded by 2^8
      const float delta = fmaxf(pm, 0.f);
      mrun += delta;
      const float corr = __builtin_amdgcn_exp2f(-delta);
      lrun *= corr;
#pragma unroll
      for (int i = 0; i < 16; ++i) { ov0[i] *= corr; ov1[i] *= corr; }
#pragma unroll
      for (int t = 0; t < 2; ++t)
#pragma unroll
        for (int i = 0; i < 16; ++i) st[t][i] -= delta;
    }

    float ps0 = 0.f, ps1 = 0.f;
#pragma unroll
    for (int t = 0; t < 2; ++t)
#pragma unroll
      for (int i = 0; i < 16; i += 2) {
        const float p0 = __builtin_amdgcn_exp2f(st[t][i]);
        const float p1 = __builtin_amdgcn_exp2f(st[t][i + 1]);
        st[t][i] = p0; st[t][i + 1] = p1;
        ps0 += p0; ps1 += p1;
      }
    float psum = ps0 + ps1;
    psum += __shfl_xor(psum, 32);
    lrun += psum;

    // PV: out^T[d][tq] += V^T[d][tk] * P^T[tk][tq], 4 k-steps of 16 tk
#pragma unroll
    for (int s = 0; s < 4; ++s) {
      const int t = s >> 1, base = (s & 1) * 8;
      unsigned c0 = cvtpk(st[t][base + 0], st[t][base + 1]);
      unsigned c1 = cvtpk(st[t][base + 2], st[t][base + 3]);
      unsigned c2 = cvtpk(st[t][base + 4], st[t][base + 5]);
      unsigned c3 = cvtpk(st[t][base + 6], st[t][base + 7]);
      asm("v_permlane32_swap_b32 %0, %1" : "+v"(c0), "+v"(c2));
      asm("v_permlane32_swap_b32 %0, %1" : "+v"(c1), "+v"(c3));
      union { short8 v; unsigned u[4]; } bu;
      bu.u[0] = c0; bu.u[1] = c1; bu.u[2] = c2; bu.u[3] = c3;
      __builtin_amdgcn_s_setprio(1);
#pragma unroll
      for (int dt = 0; dt < 2; ++dt) {
        const int row = dt * 32 + l31;
        const short8 av = *(const short8*)(Vs + row * 64 + (((s * 2 + half) ^ (l31 & 7)) * 8));
        if (dt == 0) ov0 = __builtin_amdgcn_mfma_f32_32x32x16_bf16(av, bu.v, ov0, 0, 0, 0);
        else         ov1 = __builtin_amdgcn_mfma_f32_32x32x16_bf16(av, bu.v, ov1, 0, 0, 0);
      }
      __builtin_amdgcn_s_setprio(0);
    }
    __syncthreads();
  }

  // epilogue: normalize, bounce through LDS (XOR-swizzled) for coalesced stores
  const float inv = 1.f / lrun;
  bf16_t* obuf = smem + wave * 2048;  // 32 rows x 64 d per wave
#pragma unroll
  for (int k = 0; k < 4; ++k) {
    usx4 w0 = { f2bf(ov0[4 * k + 0] * inv), f2bf(ov0[4 * k + 1] * inv),
                f2bf(ov0[4 * k + 2] * inv), f2bf(ov0[4 * k + 3] * inv) };
    *(usx4*)(obuf + l31 * 64 + ((k ^ (l31 & 7)) * 8) + half * 4) = w0;
    usx4 w1 = { f2bf(ov1[4 * k + 0] * inv), f2bf(ov1[4 * k + 1] * inv),
                f2bf(ov1[4 * k + 2] * inv), f2bf(ov1[4 * k + 3] * inv) };
    *(usx4*)(obuf + l31 * 64 + (((4 + k) ^ (l31 & 7)) * 8) + half * 4) = w1;
  }
  __syncthreads();
  const int r = lane >> 1;
  const int cb = (lane & 1) * 4;
  const size_t orow = (size_t)(b * T_SEQ + qblk * 128 + wave * 32 + r) * 1024 + h * 64;
#pragma unroll
  for (int c = 0; c < 4; ++c) {
    const int ch = cb + c;
    const short8 v = *(const short8*)(obuf + r * 64 + ((ch ^ (r & 7)) * 8));
    *(short8*)(ao + orow + ch * 8) = v;
  }
}

// ---------------- launch ----------------
extern "C" void kernel_launch(void* const* d_in, const int* in_sizes, int n_in,
                              void* d_out, int out_size, void* d_ws, size_t ws_size,
                              hipStream_t stream) {
  const float* k_in  = (const float*)d_in[0];
  const float* q_in  = (const float*)d_in[1];
  const float* v_in  = (const float*)d_in[2];
  const float* w_key = (const float*)d_in[3];
  const float* w_qry = (const float*)d_in[4];
  const float* w_val = (const float*)d_in[5];
  const float* w_prj = (const float*)d_in[6];

  char* ws = (char*)d_ws;
  bf16_t* wt = (bf16_t*)(ws);                      //  8 MB: 4 transposed weights
  bf16_t* qh = (bf16_t*)(ws + ( 8u << 20));        // 16 MB (pre-scaled by 0.125*log2e)
  bf16_t* kh = (bf16_t*)(ws + (24u << 20));        // 16 MB
  bf16_t* vt = (bf16_t*)(ws + (40u << 20));        // 16 MB (V transposed per head)
  bf16_t* ao = (bf16_t*)(ws + (56u << 20));        // 16 MB attention output

  wtrans<<<dim3(32, 32, 4), 256, 0, stream>>>(w_key, w_qry, w_val, w_prj, wt);

  gemm128<0, true><<<dim3(8, 64), 256, 0, stream>>>(k_in, wt + 0 * (1u << 20), kh, 1024);
  gemm128<1, true><<<dim3(8, 64), 256, 0, stream>>>(q_in, wt + 1 * (1u << 20), qh, 1024);
  gemm128<2, true><<<dim3(8, 64), 256, 0, stream>>>(v_in, wt + 2 * (1u << 20), vt, 1024);

  attn_fwd<<<dim3(16, 64), 256, 0, stream>>>(qh, kh, vt, ao);

  gemm128<3, false><<<dim3(8, 64), 256, 0, stream>>>(ao, wt + 3 * (1u << 20), d_out, 1024);
}